// Round 19
// baseline (252.591 us; speedup 1.0000x reference)
//
#include <hip/hip_runtime.h>
#include <hip/hip_bf16.h>
#include <stdint.h>

#define DEV __device__ __forceinline__

constexpr int BATCH = 8;

constexpr int il2(int n) { return (n <= 1) ? 0 : 1 + il2(n / 2); }

DEV float ldy(const float* p, int i) { return p[i]; }
DEV float ldy(const __hip_bfloat16* p, int i) { return __bfloat162float(p[i]); }
DEV void sty(float* p, size_t i, float v) { p[i] = v; }
DEV void sty(__hip_bfloat16* p, size_t i, float v) { p[i] = __float2bfloat16(v); }

DEV uint32_t f2bf(float v) {
  __hip_bfloat16 h = __float2bfloat16(v);
  return (uint32_t)*reinterpret_cast<uint16_t*>(&h);
}
DEV float bflo(uint32_t u) {
  uint32_t t = u << 16;
  float f;
  __builtin_memcpy(&f, &t, 4);
  return f;
}
DEV float bfhi(uint32_t u) {
  uint32_t t = u & 0xffff0000u;
  float f;
  __builtin_memcpy(&f, &t, 4);
  return f;
}
constexpr uint32_t NEGINF_BF = 0xFF80u;  // bf16 -inf
// XCD-aware swizzle (bijective when nwg % 8 == 0)
DEV int xswz(int o, int nwg) { return (o & 7) * (nwg >> 3) + (o >> 3); }

// ---------------- maskA: int32 mask -> m0, m1, m2 (fused pyramid, LDS-tiled) ----------------
__global__ __launch_bounds__(256) void maskA_k(const int* __restrict__ msk,
                                               uint8_t* __restrict__ m0,
                                               uint8_t* __restrict__ m1,
                                               uint8_t* __restrict__ m2) {
  __shared__ uint8_t t0[32768];
  __shared__ uint8_t t1[4096];
  int blk = blockIdx.x;
  int bx = (blk & 3) * 32, by = ((blk >> 2) & 3) * 32, bz = ((blk >> 4) & 3) * 32, b = blk >> 6;
  int tid = threadIdx.x;
  for (int g = tid; g < 8192; g += 256) {
    int gx4 = (g & 7) * 4, gy = (g >> 3) & 31, gz = g >> 8;
    int gidx = ((b * 128 + bz + gz) * 128 + by + gy) * 128 + bx + gx4;
    int4 v = *(const int4*)(msk + gidx);
    uint32_t o = (v.x ? 1u : 0u) | (v.y ? 256u : 0u) | (v.z ? 65536u : 0u) | (v.w ? 16777216u : 0u);
    ((uint32_t*)t0)[g] = o;
    ((uint32_t*)m0)[gidx >> 2] = o;
  }
  __syncthreads();
  for (int j = tid; j < 4096; j += 256) {
    int ox = j & 15, oy = (j >> 4) & 15, oz = j >> 8;
    uint32_t act = 0;
#pragma unroll
    for (int dz = 0; dz < 2; dz++)
#pragma unroll
      for (int dy = 0; dy < 2; dy++)
        act |= *(const uint16_t*)&t0[(2 * oz + dz) * 1024 + (2 * oy + dy) * 32 + 2 * ox];
    uint8_t vv = act ? 1 : 0;
    t1[j] = vv;
    m1[((b * 64 + bz / 2 + oz) * 64 + by / 2 + oy) * 64 + bx / 2 + ox] = vv;
  }
  __syncthreads();
  for (int j = tid; j < 512; j += 256) {
    int ox = j & 7, oy = (j >> 3) & 7, oz = j >> 6;
    uint32_t act = 0;
#pragma unroll
    for (int dz = 0; dz < 2; dz++)
#pragma unroll
      for (int dy = 0; dy < 2; dy++)
        act |= *(const uint16_t*)&t1[(2 * oz + dz) * 256 + (2 * oy + dy) * 16 + 2 * ox];
    m2[((b * 32 + bz / 4 + oz) * 32 + by / 4 + oy) * 32 + bx / 4 + ox] = act ? 1 : 0;
  }
}

// ---------------- maskB: m2 -> m3, m4, m5, m6 (single block) ----------------
__global__ __launch_bounds__(1024) void maskB_k(const uint8_t* __restrict__ m2,
                                                uint8_t* __restrict__ m3,
                                                uint8_t* __restrict__ m4,
                                                uint8_t* __restrict__ m5,
                                                uint8_t* __restrict__ m6) {
  __shared__ uint8_t t3[32768];
  __shared__ uint8_t t4[4096];
  __shared__ uint8_t t5[512];
  int tid = threadIdx.x;
  for (int j = tid; j < 32768; j += 1024) {
    int ox = j & 15, oy = (j >> 4) & 15, oz = (j >> 8) & 15, b = j >> 12;
    uint32_t act = 0;
#pragma unroll
    for (int dz = 0; dz < 2; dz++)
#pragma unroll
      for (int dy = 0; dy < 2; dy++)
        act |= *(const uint16_t*)&m2[((b * 32 + 2 * oz + dz) * 32 + 2 * oy + dy) * 32 + 2 * ox];
    uint8_t v = act ? 1 : 0;
    t3[j] = v;
    m3[j] = v;
  }
  __syncthreads();
  for (int j = tid; j < 4096; j += 1024) {
    int ox = j & 7, oy = (j >> 3) & 7, oz = (j >> 6) & 7, b = j >> 9;
    uint32_t act = 0;
#pragma unroll
    for (int dz = 0; dz < 2; dz++)
#pragma unroll
      for (int dy = 0; dy < 2; dy++)
        act |= *(const uint16_t*)&t3[((b * 16 + 2 * oz + dz) * 16 + 2 * oy + dy) * 16 + 2 * ox];
    uint8_t v = act ? 1 : 0;
    t4[j] = v;
    m4[j] = v;
  }
  __syncthreads();
  if (tid < 512) {
    int j = tid;
    int ox = j & 3, oy = (j >> 2) & 3, oz = (j >> 4) & 3, b = j >> 6;
    uint32_t act = 0;
#pragma unroll
    for (int dz = 0; dz < 2; dz++)
#pragma unroll
      for (int dy = 0; dy < 2; dy++)
        act |= *(const uint16_t*)&t4[((b * 8 + 2 * oz + dz) * 8 + 2 * oy + dy) * 8 + 2 * ox];
    uint8_t v = act ? 1 : 0;
    t5[j] = v;
    m5[j] = v;
  }
  __syncthreads();
  if (tid < 64) {
    int j = tid;
    int ox = j & 1, oy = (j >> 1) & 1, oz = (j >> 2) & 1, b = j >> 3;
    uint32_t act = 0;
#pragma unroll
    for (int dz = 0; dz < 2; dz++)
#pragma unroll
      for (int dy = 0; dy < 2; dy++)
        act |= *(const uint16_t*)&t5[((b * 4 + 2 * oz + dz) * 4 + 2 * oy + dy) * 4 + 2 * ox];
    m6[j] = act ? 1 : 0;
  }
}

// ---------------- layer 0 conv: 16x16x8 tile; row-per-thread staging; 4 blocks/CU -----------
// Thread tid owns halo row tid (180 active): ONE row->(sz,sy) division, 6 float4 + 6 u32 loads
// at immediate offsets off one base, 24 ds_write_b32 at immediate offsets. (256,4): no spill.
__global__ __launch_bounds__(256, 4) void conv0_k(const float* __restrict__ x,
                                                  const uint8_t* __restrict__ m0,
                                                  const float* __restrict__ w,  // [27][1][2]
                                                  __hip_bfloat16* __restrict__ y0,
                                                  float* __restrict__ partials) {
  constexpr int SR = 26;     // LDS row stride (floats); slots 1..24 used
  constexpr int NROW = 180;  // 18 y * 10 z
  __shared__ float sx[NROW * SR];
  __shared__ float sm[4][5];
  int blk = xswz(blockIdx.x, 8192);
  int tx0 = (blk & 7) * 16, ty0 = ((blk >> 3) & 7) * 16, tz0 = ((blk >> 6) & 15) * 8,
      b = blk >> 10;
  int tid = threadIdx.x;

  // staging: one halo row per thread (row = tid < 180)
  {
    int row = tid;
    unsigned sz = ((unsigned)row * 3641u) >> 16;  // row/18 (valid row<2000)
    int sy = row - (int)sz * 18;
    int gz = tz0 + (int)sz - 1, gy = ty0 + sy - 1;
    bool okrow = (row < NROW) & ((unsigned)gz < 128u) & ((unsigned)gy < 128u);
    int gibase = ((b * 128 + gz) * 128 + gy) * 128 + tx0 - 4;
    // quad validity: block-uniform (tx0-4+4k in [0,128))
    float4 xq[6];
    uint32_t mq[6];
#pragma unroll
    for (int k = 0; k < 6; k++) {
      bool okk = (unsigned)(tx0 - 4 + 4 * k) < 128u;  // wave-uniform
      bool ok = okrow & okk;
      int gi = ok ? gibase + 4 * k : 0;
      xq[k] = *(const float4*)(x + gi);
      uint32_t mr = *(const uint32_t*)(m0 + gi);
      mq[k] = ok ? mr : 0u;
    }
    if (row < NROW) {
      int base = row * SR + 1;
      float vals[4];
#pragma unroll
      for (int k = 0; k < 6; k++) {
        vals[0] = xq[k].x;
        vals[1] = xq[k].y;
        vals[2] = xq[k].z;
        vals[3] = xq[k].w;
        uint32_t mw = mq[k];
#pragma unroll
        for (int e = 0; e < 4; e++)
          sx[base + 4 * k + e] = ((mw >> (8 * e)) & 0xffu) ? vals[e] : 0.f;
      }
    }
  }
  __syncthreads();

  int tc = tid & 7, tb = (tid >> 3) & 7, ta = tid >> 6;  // ta 0..3
  int lx = tc * 2, ly = tb * 2, lz = ta * 2;

  // hoist stat-mask loads (L2-hot)
  uint32_t mm[2][2];
#pragma unroll
  for (int oz = 0; oz < 2; oz++)
#pragma unroll
    for (int oy = 0; oy < 2; oy++) {
      int z = tz0 + lz + oz, y = ty0 + ly + oy, xx = tx0 + lx;
      mm[oz][oy] = *(const uint16_t*)(m0 + ((b * 128 + z) * 128 + y) * 128 + xx);
    }

  float acc[2][2][2][2];
#pragma unroll
  for (int oz = 0; oz < 2; oz++)
#pragma unroll
    for (int oy = 0; oy < 2; oy++)
#pragma unroll
      for (int ox = 0; ox < 2; ox++)
        acc[oz][oy][ox][0] = acc[oz][oy][ox][1] = 0.f;

  // z-plane streaming; pl[yy][j] = input at gx = tx0+lx-1+j (slot lx+4+j, even base -> b64)
#pragma unroll
  for (int p = 0; p < 4; p++) {
    float pl[4][4];
#pragma unroll
    for (int yy = 0; yy < 4; yy++)
#pragma unroll
      for (int j = 0; j < 4; j += 2) {
        float2 v = *(const float2*)&sx[((lz + p) * 18 + (ly + yy)) * SR + lx + 4 + j];
        pl[yy][j] = v.x;
        pl[yy][j + 1] = v.y;
      }
#pragma unroll
    for (int oz = 0; oz < 2; oz++) {
      int dz = p - oz;
      if (dz < 0 || dz > 2) continue;
#pragma unroll
      for (int dy = 0; dy < 3; dy++)
#pragma unroll
        for (int dx = 0; dx < 3; dx++) {
          float w0 = w[((dz * 3 + dy) * 3 + dx) * 2];
          float w1 = w[((dz * 3 + dy) * 3 + dx) * 2 + 1];
#pragma unroll
          for (int oy = 0; oy < 2; oy++)
#pragma unroll
            for (int ox = 0; ox < 2; ox++) {
              float s = pl[oy + dy][ox + dx];
              acc[oz][oy][ox][0] = fmaf(s, w0, acc[oz][oy][ox][0]);
              acc[oz][oy][ox][1] = fmaf(s, w1, acc[oz][oy][ox][1]);
            }
        }
    }
  }

  // store (-inf at inactive) + masked stats
  float s0 = 0.f, q0 = 0.f, s1 = 0.f, q1 = 0.f;
  int cnt2 = 0;
#pragma unroll
  for (int oz = 0; oz < 2; oz++)
#pragma unroll
    for (int oy = 0; oy < 2; oy++) {
      int z = tz0 + lz + oz, y = ty0 + ly + oy, xx = tx0 + lx;
      int vo = ((b * 128 + z) * 128 + y) * 128 + xx;
      uint32_t m2b = mm[oz][oy];
      uint2 st;
      if (m2b & 0xff) {
        st.x = f2bf(acc[oz][oy][0][0]) | (f2bf(acc[oz][oy][0][1]) << 16);
        s0 += acc[oz][oy][0][0];
        q0 += acc[oz][oy][0][0] * acc[oz][oy][0][0];
        s1 += acc[oz][oy][0][1];
        q1 += acc[oz][oy][0][1] * acc[oz][oy][0][1];
        cnt2++;
      } else {
        st.x = NEGINF_BF | (NEGINF_BF << 16);
      }
      if (m2b >> 8) {
        st.y = f2bf(acc[oz][oy][1][0]) | (f2bf(acc[oz][oy][1][1]) << 16);
        s0 += acc[oz][oy][1][0];
        q0 += acc[oz][oy][1][0] * acc[oz][oy][1][0];
        s1 += acc[oz][oy][1][1];
        q1 += acc[oz][oy][1][1] * acc[oz][oy][1][1];
        cnt2++;
      } else {
        st.y = NEGINF_BF | (NEGINF_BF << 16);
      }
      ((uint2*)y0)[vo >> 1] = st;
    }
  float cf = (float)cnt2;
#pragma unroll
  for (int off = 32; off >= 1; off >>= 1) {
    s0 += __shfl_xor(s0, off);
    q0 += __shfl_xor(q0, off);
    s1 += __shfl_xor(s1, off);
    q1 += __shfl_xor(q1, off);
    cf += __shfl_xor(cf, off);
  }
  int wave = tid >> 6;
  if ((tid & 63) == 0) {
    sm[wave][0] = s0;
    sm[wave][1] = q0;
    sm[wave][2] = s1;
    sm[wave][3] = q1;
    sm[wave][4] = cf;
  }
  __syncthreads();
  if (tid < 5) {
    float t = 0.f;
#pragma unroll
    for (int wv = 0; wv < 4; wv++) t += sm[wv][tid];
    partials[blk * 5 + tid] = t;
  }
}

// ---------------- LDS-tiled stride-2 conv (bf16 in); -inf sentinel -------------------------
// Cin==2: quad-of-voxels uint4 staging. Cin==4: voxel-pair uint4 staging.
template <int Din, int Cin, int Cout, int TZ, typename Tin, typename Tout>
__global__ __launch_bounds__(64 * TZ, 4) void conv_tile_k(const Tin* __restrict__ yin,
                                                          const uint8_t* __restrict__ mo,
                                                          const float* __restrict__ ssin,
                                                          const float* __restrict__ w,
                                                          Tout* __restrict__ yout,
                                                          float* __restrict__ partials) {
  static_assert(sizeof(Tin) == 2 && (Cin == 2 || Cin == 4), "bf16 input only");
  constexpr int Dout = Din / 2;
  constexpr int NT = 64 * TZ;
  constexpr int IZ = 2 * TZ + 1;
  constexpr int NROW = 17 * IZ;
  constexpr int NTASK = (Cin == 2) ? NROW * 5 : NROW * 9;
  constexpr int PR = (NTASK + NT - 1) / NT;
  constexpr int TXN = Dout / 8;
  constexpr int TZN = Dout / TZ;
  constexpr int LTX = il2(TXN);
  constexpr int LTZ = il2(TZN);
  constexpr int NWG = TXN * TXN * TZN * BATCH;
  constexpr int REC = 2 * Cout + 1;
  __shared__ float sx[289 * IZ * Cin];
  __shared__ float sm[TZ][REC];

  int tid = threadIdx.x;
  int blk = xswz(blockIdx.x, NWG);
  int tx0 = (blk & (TXN - 1)) * 8;
  int ty0 = ((blk >> LTX) & (TXN - 1)) * 8;
  int tz0 = ((blk >> (2 * LTX)) & (TZN - 1)) * TZ;
  int b = blk >> (2 * LTX + LTZ);

  float sc[Cin], sh[Cin];
#pragma unroll
  for (int ci = 0; ci < Cin; ci++) {
    sc[ci] = ssin[2 * ci];
    sh[ci] = ssin[2 * ci + 1];
  }

  int oy0 = 2 * ty0 - 1, oz0 = 2 * tz0 - 1;
  // phase 1: issue all staging loads (clamped addresses)
  uint4 pv[PR];
  uint32_t okb = 0;
#pragma unroll
  for (int r = 0; r < PR; r++) {
    int i = tid + r * NT;
    if constexpr (Cin == 2) {
      int row = i / 5, qq = i - 5 * row;
      int sz = row / 17, sy = row - 17 * sz;
      int gz = oz0 + sz, gy = oy0 + sy;
      int px = 2 * tx0 - 4 + 4 * qq;  // 4-voxel window [2tx0-4, 2tx0+16)
      bool ok = (i < NTASK) & ((unsigned)gz < (unsigned)Din) & ((unsigned)gy < (unsigned)Din) &
                (px >= 0);
      int gi = ok ? ((b * Din + gz) * Din + gy) * Din + px : 0;
      if (ok) okb |= (1u << r);
      pv[r] = *(const uint4*)((const uint16_t*)yin + (size_t)gi * 2);
    } else {
      int row = i / 9, qq = i - 9 * row;
      int sz = row / 17, sy = row - 17 * sz;
      int gz = oz0 + sz, gy = oy0 + sy;
      int px = 2 * tx0 - 2 + 2 * qq;  // voxel pair
      bool ok = (i < NTASK) & ((unsigned)gz < (unsigned)Din) & ((unsigned)gy < (unsigned)Din) &
                (px >= 0);
      int gi = ok ? ((b * Din + gz) * Din + gy) * Din + px : 0;
      if (ok) okb |= (1u << r);
      pv[r] = *(const uint4*)((const uint16_t*)yin + (size_t)gi * 4);
    }
  }
  // phase 2: BN+ReLU then LDS writes (-inf sentinel -> 0 automatically)
#pragma unroll
  for (int r = 0; r < PR; r++) {
    int i = tid + r * NT;
    if (i >= NTASK) continue;
    bool ok = (okb >> r) & 1u;
    if constexpr (Cin == 2) {
      int row = i / 5, qq = i - 5 * row;
      uint32_t vox[4] = {pv[r].x, pv[r].y, pv[r].z, pv[r].w};
#pragma unroll
      for (int e = 0; e < 4; e++) {
        int u = 4 * qq + e - 3;
        if ((unsigned)u >= 17u) continue;
        int site = row * 17 + u;
        float f0 = ok ? fmaxf(fmaf(bflo(vox[e]), sc[0], sh[0]), 0.f) : 0.f;
        float f1 = ok ? fmaxf(fmaf(bfhi(vox[e]), sc[1], sh[1]), 0.f) : 0.f;
        *(float2*)&sx[site * 2] = make_float2(f0, f1);
      }
    } else {
      int row = i / 9, qq = i - 9 * row;
#pragma unroll
      for (int e = 0; e < 2; e++) {
        int u = 2 * qq - 1 + e;
        if ((unsigned)u >= 17u) continue;
        int site = row * 17 + u;
        uint32_t va = e ? pv[r].z : pv[r].x;
        uint32_t vb = e ? pv[r].w : pv[r].y;
        float f0 = ok ? fmaxf(fmaf(bflo(va), sc[0], sh[0]), 0.f) : 0.f;
        float f1 = ok ? fmaxf(fmaf(bfhi(va), sc[1], sh[1]), 0.f) : 0.f;
        float f2 = ok ? fmaxf(fmaf(bflo(vb), sc[2], sh[2]), 0.f) : 0.f;
        float f3 = ok ? fmaxf(fmaf(bfhi(vb), sc[3], sh[3]), 0.f) : 0.f;
        *(float4*)&sx[site * 4] = make_float4(f0, f1, f2, f3);
      }
    }
  }
  __syncthreads();

  int tc = tid & 7, tb = (tid >> 3) & 7, ta = tid >> 6;
  int lx = tc, ly = tb, lz = ta;
  int vo = ((b * Dout + tz0 + lz) * Dout + ty0 + ly) * Dout + tx0 + lx;
  bool act = mo[vo] != 0;
  float acc[Cout];
#pragma unroll
  for (int co = 0; co < Cout; co++) acc[co] = 0.f;
  if (act) {
    int base = ((2 * lz) * 289 + (2 * ly) * 17 + (2 * lx)) * Cin;
#pragma unroll
    for (int dz = 0; dz < 3; dz++)
#pragma unroll
      for (int dy = 0; dy < 3; dy++)
#pragma unroll
        for (int dx = 0; dx < 3; dx++) {
          int off = base + (dz * 289 + dy * 17 + dx) * Cin;
          const float* wp = w + ((dz * 3 + dy) * 3 + dx) * Cin * Cout;
#pragma unroll
          for (int ci = 0; ci < Cin; ci++) {
            float s = sx[off + ci];
#pragma unroll
            for (int co = 0; co < Cout; co++)
              acc[co] = fmaf(s, wp[ci * Cout + co], acc[co]);
          }
        }
  }
  {
    uint32_t pk[Cout / 2];
    if (act) {
#pragma unroll
      for (int k = 0; k < Cout / 2; k++) pk[k] = f2bf(acc[2 * k]) | (f2bf(acc[2 * k + 1]) << 16);
    } else {
#pragma unroll
      for (int k = 0; k < Cout / 2; k++) pk[k] = NEGINF_BF | (NEGINF_BF << 16);
    }
    if constexpr (Cout == 4)
      *(uint2*)((uint16_t*)yout + (size_t)vo * 4) = *(uint2*)pk;
    else if constexpr (Cout == 8)
      *(uint4*)((uint16_t*)yout + (size_t)vo * 8) = *(uint4*)pk;
    else {
#pragma unroll
      for (int k = 0; k < Cout / 2; k++)
        *((uint32_t*)yout + (size_t)vo * (Cout / 2) + k) = pk[k];
    }
  }
  unsigned long long bal = __ballot(act);
  int wave = tid >> 6, lane = tid & 63;
#pragma unroll
  for (int co = 0; co < Cout; co++) {
    float s = acc[co], q = acc[co] * acc[co];
#pragma unroll
    for (int off = 32; off >= 1; off >>= 1) {
      s += __shfl_xor(s, off);
      q += __shfl_xor(q, off);
    }
    if (lane == 0) {
      sm[wave][2 * co] = s;
      sm[wave][2 * co + 1] = q;
    }
  }
  if (lane == 0) sm[wave][2 * Cout] = (float)__popcll(bal);
  __syncthreads();
  if (tid < REC) {
    float t = 0.f;
#pragma unroll
    for (int wv = 0; wv < TZ; wv++) t += sm[wv][tid];
    partials[(size_t)blk * REC + tid] = t;
  }
}

// ---------------- generic stride-2 conv (small layers); -inf sentinel input ----------------
template <int Din, int Cin, int Cout, typename Tin, typename Tout>
__global__ __launch_bounds__(256) void conv_s2_k(const Tin* __restrict__ yin,
                                                 const uint8_t* __restrict__ mo,
                                                 const float* __restrict__ ssin,
                                                 const float* __restrict__ w,
                                                 Tout* __restrict__ yout,
                                                 float* __restrict__ partials) {
  constexpr int Dout = Din / 2;
  constexpr int LD = il2(Dout);
  constexpr int LC = il2(Cout);
  constexpr int REC = 2 * Cout + 1;
  int tid = threadIdx.x;
  int lin = blockIdx.x * 256 + tid;
  int co = lin & (Cout - 1);
  int v = lin >> LC;
  int x = v & (Dout - 1);
  int y = (v >> LD) & (Dout - 1);
  int z = (v >> (2 * LD)) & (Dout - 1);
  int b = v >> (3 * LD);
  bool act = mo[v] != 0;
  float acc = 0.f;
  if (act) {
    for (int dz = 0; dz < 3; dz++) {
      int iz = 2 * z + dz - 1;
      if ((unsigned)iz >= (unsigned)Din) continue;
      for (int dy = 0; dy < 3; dy++) {
        int iy = 2 * y + dy - 1;
        if ((unsigned)iy >= (unsigned)Din) continue;
        for (int dx = 0; dx < 3; dx++) {
          int ix = 2 * x + dx - 1;
          if ((unsigned)ix >= (unsigned)Din) continue;
          int gi = ((b * Din + iz) * Din + iy) * Din + ix;
          const float* wp = w + ((dz * 3 + dy) * 3 + dx) * Cin * Cout + co;
          float f[Cin];
          if constexpr (sizeof(Tin) == 2 && Cin == 8) {
            uint4 rr = *(const uint4*)((const uint16_t*)yin + (size_t)gi * 8);
            f[0] = bflo(rr.x);
            f[1] = bfhi(rr.x);
            f[2] = bflo(rr.y);
            f[3] = bfhi(rr.y);
            f[4] = bflo(rr.z);
            f[5] = bfhi(rr.z);
            f[6] = bflo(rr.w);
            f[7] = bfhi(rr.w);
          } else if constexpr (sizeof(Tin) == 4 && (Cin % 4) == 0) {
            const float* yp = (const float*)yin + (size_t)gi * Cin;
#pragma unroll
            for (int c4 = 0; c4 < Cin; c4 += 4) {
              float4 vv = *(const float4*)(yp + c4);
              f[c4] = vv.x;
              f[c4 + 1] = vv.y;
              f[c4 + 2] = vv.z;
              f[c4 + 3] = vv.w;
            }
          } else {
            const Tin* yp = yin + (size_t)gi * Cin;
#pragma unroll
            for (int ci = 0; ci < Cin; ci++) f[ci] = ldy(yp, ci);
          }
#pragma unroll
          for (int ci = 0; ci < Cin; ci++) {
            float val = fmaxf(fmaf(f[ci], ssin[2 * ci], ssin[2 * ci + 1]), 0.f);
            acc = fmaf(val, wp[ci * Cout], acc);
          }
        }
      }
    }
  }
  sty(yout, (size_t)lin, act ? acc : -INFINITY);
  float s = acc, q = acc * acc;
#pragma unroll
  for (int off = 32; off >= Cout; off >>= 1) {
    s += __shfl_xor(s, off);
    q += __shfl_xor(q, off);
  }
  unsigned long long bal = __ballot(act && co == 0);
  __shared__ float sm[4][REC];
  int wave = tid >> 6, lane = tid & 63;
  if (lane < Cout) {
    sm[wave][2 * lane] = s;
    sm[wave][2 * lane + 1] = q;
  }
  if (lane == 0) sm[wave][2 * Cout] = (float)__popcll(bal);
  __syncthreads();
  if (tid < REC)
    partials[(size_t)blockIdx.x * REC + tid] = sm[0][tid] + sm[1][tid] + sm[2][tid] + sm[3][tid];
}

// ---------------- stat reduce: partials -> per-channel (scale, shift) ----------------
template <int Cout>
__global__ __launch_bounds__(256) void stats_k(const float* __restrict__ partials, int nblocks,
                                               const float* __restrict__ g,
                                               const float* __restrict__ bb,
                                               float* __restrict__ ss) {
  constexpr int REC = 2 * Cout + 1;
  int c = blockIdx.x, tid = threadIdx.x;
  float s = 0.f, q = 0.f, n = 0.f;
  for (int i = tid; i < nblocks; i += 256) {
    const float* p = partials + (size_t)i * REC;
    s += p[2 * c];
    q += p[2 * c + 1];
    n += p[2 * Cout];
  }
  __shared__ float S[256], Q[256], N[256];
  S[tid] = s;
  Q[tid] = q;
  N[tid] = n;
  __syncthreads();
  for (int st = 128; st > 0; st >>= 1) {
    if (tid < st) {
      S[tid] += S[tid + st];
      Q[tid] += Q[tid + st];
      N[tid] += N[tid + st];
    }
    __syncthreads();
  }
  if (tid == 0) {
    float cnt = fmaxf(N[0], 1.f);
    float mean = S[0] / cnt;
    float var = Q[0] / cnt - mean * mean;
    float scale = g[c] * rsqrtf(var + 1e-5f);
    ss[2 * c] = scale;
    ss[2 * c + 1] = bb[c] - mean * scale;
  }
}

// ---------------- final: fused stats<64> + sparse max pool (-inf sentinel input) -------------
__global__ __launch_bounds__(512) void pool_stats_k(const float* __restrict__ y5,
                                                    const uint8_t* __restrict__ m6,
                                                    const float* __restrict__ partials,  // 128x129
                                                    const float* __restrict__ g,
                                                    const float* __restrict__ bb,
                                                    float* __restrict__ out) {
  __shared__ float ssc[64], ssh[64];
  int b = blockIdx.x, tid = threadIdx.x;
  if (tid < 64) {
    float s = 0.f, q = 0.f, n = 0.f;
    for (int i = 0; i < 128; i++) {
      const float* p = partials + i * 129;
      s += p[2 * tid];
      q += p[2 * tid + 1];
      n += p[128];
    }
    float cnt = fmaxf(n, 1.f);
    float mean = s / cnt;
    float var = q / cnt - mean * mean;
    float scale = g[tid] * rsqrtf(var + 1e-5f);
    ssc[tid] = scale;
    ssh[tid] = bb[tid] - mean * scale;
  }
  __syncthreads();
  int c = tid & 63, s = tid >> 6;
  int qx = s & 1, qy = (s >> 1) & 1, qz = (s >> 2) & 1;
  int ov = ((b * 2 + qz) * 2 + qy) * 2 + qx;
  float scale = ssc[c], shift = ssh[c];
  float mx = 0.f;
  for (int dz = 0; dz < 3; dz++) {
    int iz = 2 * qz + dz - 1;
    if ((unsigned)iz >= 4u) continue;
    for (int dy = 0; dy < 3; dy++) {
      int iy = 2 * qy + dy - 1;
      if ((unsigned)iy >= 4u) continue;
      for (int dx = 0; dx < 3; dx++) {
        int ix = 2 * qx + dx - 1;
        if ((unsigned)ix >= 4u) continue;
        int gi = ((b * 4 + iz) * 4 + iy) * 4 + ix;
        float val = fmaxf(fmaf(y5[gi * 64 + c], scale, shift), 0.f);
        mx = fmaxf(mx, val);
      }
    }
  }
  // m6 gate is REQUIRED: inactive output can still see active neighbors in its 3^3 footprint
  out[ov * 64 + c] = m6[ov] ? mx : 0.f;
}

extern "C" void kernel_launch(void* const* d_in, const int* in_sizes, int n_in,
                              void* d_out, int out_size, void* d_ws, size_t ws_size,
                              hipStream_t stream) {
  const float* x = (const float*)d_in[0];
  const int* msk = (const int*)d_in[1];
  const float *w[6], *g[6], *bb[6];
  for (int i = 0; i < 6; i++) {
    w[i] = (const float*)d_in[2 + 3 * i];
    g[i] = (const float*)d_in[3 + 3 * i];
    bb[i] = (const float*)d_in[4 + 3 * i];
  }

  char* ws = (char*)d_ws;
  size_t o = 0;
  auto A = [&](size_t bytes) -> char* {
    char* p = ws + o;
    o = (o + bytes + 255) & ~(size_t)255;
    return p;
  };
  __hip_bfloat16* y0 = (__hip_bfloat16*)A(33554432 * 2);  // 64 MB
  __hip_bfloat16* y1 = (__hip_bfloat16*)A(8388608 * 2);   // 16 MB
  __hip_bfloat16* y2 = (__hip_bfloat16*)A(2097152 * 2);   // 4 MB
  float* y3 = (float*)A(2097152);
  float* y4 = (float*)A(524288);
  float* y5 = (float*)A(131072);
  uint8_t* m0 = (uint8_t*)A(16777216);
  uint8_t* m1 = (uint8_t*)A(2097152);
  uint8_t* m2 = (uint8_t*)A(262144);
  uint8_t* m3 = (uint8_t*)A(32768);
  uint8_t* m4 = (uint8_t*)A(4096);
  uint8_t* m5 = (uint8_t*)A(512);
  uint8_t* m6 = (uint8_t*)A(64);
  float* part = (float*)A(2 << 20);
  float* ss = (float*)A(4096);
  if (o > ws_size) return;  // cannot run safely

  maskA_k<<<512, 256, 0, stream>>>(msk, m0, m1, m2);
  maskB_k<<<1, 1024, 0, stream>>>(m2, m3, m4, m5, m6);

  conv0_k<<<8192, 256, 0, stream>>>(x, m0, w[0], y0, part);
  stats_k<2><<<2, 256, 0, stream>>>(part, 8192, g[0], bb[0], ss + 0);
  conv_tile_k<128, 2, 4, 4, __hip_bfloat16, __hip_bfloat16>
      <<<8192, 256, 0, stream>>>(y0, m1, ss + 0, w[1], y1, part);
  stats_k<4><<<4, 256, 0, stream>>>(part, 8192, g[1], bb[1], ss + 128);
  conv_tile_k<64, 4, 8, 4, __hip_bfloat16, __hip_bfloat16>
      <<<1024, 256, 0, stream>>>(y1, m2, ss + 128, w[2], y2, part);
  stats_k<8><<<8, 256, 0, stream>>>(part, 1024, g[2], bb[2], ss + 256);
  conv_s2_k<32, 8, 16, __hip_bfloat16, float>
      <<<2048, 256, 0, stream>>>(y2, m3, ss + 256, w[3], y3, part);
  stats_k<16><<<16, 256, 0, stream>>>(part, 2048, g[3], bb[3], ss + 384);
  conv_s2_k<16, 16, 32, float, float>
      <<<512, 256, 0, stream>>>(y3, m4, ss + 384, w[4], y4, part);
  stats_k<32><<<32, 256, 0, stream>>>(part, 512, g[4], bb[4], ss + 512);
  conv_s2_k<8, 32, 64, float, float>
      <<<128, 256, 0, stream>>>(y4, m5, ss + 512, w[5], y5, part);
  pool_stats_k<<<8, 512, 0, stream>>>(y5, m6, part, g[5], bb[5], (float*)d_out);
}

// Round 20
// 248.388 us; speedup vs baseline: 1.0169x; 1.0169x over previous
//
#include <hip/hip_runtime.h>
#include <hip/hip_bf16.h>
#include <stdint.h>

#define DEV __device__ __forceinline__

constexpr int BATCH = 8;

constexpr int il2(int n) { return (n <= 1) ? 0 : 1 + il2(n / 2); }

DEV float ldy(const float* p, int i) { return p[i]; }
DEV float ldy(const __hip_bfloat16* p, int i) { return __bfloat162float(p[i]); }
DEV void sty(float* p, size_t i, float v) { p[i] = v; }
DEV void sty(__hip_bfloat16* p, size_t i, float v) { p[i] = __float2bfloat16(v); }

DEV uint32_t f2bf(float v) {
  __hip_bfloat16 h = __float2bfloat16(v);
  return (uint32_t)*reinterpret_cast<uint16_t*>(&h);
}
DEV float bflo(uint32_t u) {
  uint32_t t = u << 16;
  float f;
  __builtin_memcpy(&f, &t, 4);
  return f;
}
DEV float bfhi(uint32_t u) {
  uint32_t t = u & 0xffff0000u;
  float f;
  __builtin_memcpy(&f, &t, 4);
  return f;
}
constexpr uint32_t NEGINF_BF = 0xFF80u;  // bf16 -inf
// XCD-aware swizzle (bijective when nwg % 8 == 0)
DEV int xswz(int o, int nwg) { return (o & 7) * (nwg >> 3) + (o >> 3); }

// ---------------- maskA: int32 mask -> m0, m1, m2 (fused pyramid, LDS-tiled) ----------------
__global__ __launch_bounds__(256) void maskA_k(const int* __restrict__ msk,
                                               uint8_t* __restrict__ m0,
                                               uint8_t* __restrict__ m1,
                                               uint8_t* __restrict__ m2) {
  __shared__ uint8_t t0[32768];
  __shared__ uint8_t t1[4096];
  int blk = blockIdx.x;
  int bx = (blk & 3) * 32, by = ((blk >> 2) & 3) * 32, bz = ((blk >> 4) & 3) * 32, b = blk >> 6;
  int tid = threadIdx.x;
  for (int g = tid; g < 8192; g += 256) {
    int gx4 = (g & 7) * 4, gy = (g >> 3) & 31, gz = g >> 8;
    int gidx = ((b * 128 + bz + gz) * 128 + by + gy) * 128 + bx + gx4;
    int4 v = *(const int4*)(msk + gidx);
    uint32_t o = (v.x ? 1u : 0u) | (v.y ? 256u : 0u) | (v.z ? 65536u : 0u) | (v.w ? 16777216u : 0u);
    ((uint32_t*)t0)[g] = o;
    ((uint32_t*)m0)[gidx >> 2] = o;
  }
  __syncthreads();
  for (int j = tid; j < 4096; j += 256) {
    int ox = j & 15, oy = (j >> 4) & 15, oz = j >> 8;
    uint32_t act = 0;
#pragma unroll
    for (int dz = 0; dz < 2; dz++)
#pragma unroll
      for (int dy = 0; dy < 2; dy++)
        act |= *(const uint16_t*)&t0[(2 * oz + dz) * 1024 + (2 * oy + dy) * 32 + 2 * ox];
    uint8_t vv = act ? 1 : 0;
    t1[j] = vv;
    m1[((b * 64 + bz / 2 + oz) * 64 + by / 2 + oy) * 64 + bx / 2 + ox] = vv;
  }
  __syncthreads();
  for (int j = tid; j < 512; j += 256) {
    int ox = j & 7, oy = (j >> 3) & 7, oz = j >> 6;
    uint32_t act = 0;
#pragma unroll
    for (int dz = 0; dz < 2; dz++)
#pragma unroll
      for (int dy = 0; dy < 2; dy++)
        act |= *(const uint16_t*)&t1[(2 * oz + dz) * 256 + (2 * oy + dy) * 16 + 2 * ox];
    m2[((b * 32 + bz / 4 + oz) * 32 + by / 4 + oy) * 32 + bx / 4 + ox] = act ? 1 : 0;
  }
}

// ---------------- maskB: m2 -> m3, m4, m5, m6 (single block) ----------------
__global__ __launch_bounds__(1024) void maskB_k(const uint8_t* __restrict__ m2,
                                                uint8_t* __restrict__ m3,
                                                uint8_t* __restrict__ m4,
                                                uint8_t* __restrict__ m5,
                                                uint8_t* __restrict__ m6) {
  __shared__ uint8_t t3[32768];
  __shared__ uint8_t t4[4096];
  __shared__ uint8_t t5[512];
  int tid = threadIdx.x;
  for (int j = tid; j < 32768; j += 1024) {
    int ox = j & 15, oy = (j >> 4) & 15, oz = (j >> 8) & 15, b = j >> 12;
    uint32_t act = 0;
#pragma unroll
    for (int dz = 0; dz < 2; dz++)
#pragma unroll
      for (int dy = 0; dy < 2; dy++)
        act |= *(const uint16_t*)&m2[((b * 32 + 2 * oz + dz) * 32 + 2 * oy + dy) * 32 + 2 * ox];
    uint8_t v = act ? 1 : 0;
    t3[j] = v;
    m3[j] = v;
  }
  __syncthreads();
  for (int j = tid; j < 4096; j += 1024) {
    int ox = j & 7, oy = (j >> 3) & 7, oz = (j >> 6) & 7, b = j >> 9;
    uint32_t act = 0;
#pragma unroll
    for (int dz = 0; dz < 2; dz++)
#pragma unroll
      for (int dy = 0; dy < 2; dy++)
        act |= *(const uint16_t*)&t3[((b * 16 + 2 * oz + dz) * 16 + 2 * oy + dy) * 16 + 2 * ox];
    uint8_t v = act ? 1 : 0;
    t4[j] = v;
    m4[j] = v;
  }
  __syncthreads();
  if (tid < 512) {
    int j = tid;
    int ox = j & 3, oy = (j >> 2) & 3, oz = (j >> 4) & 3, b = j >> 6;
    uint32_t act = 0;
#pragma unroll
    for (int dz = 0; dz < 2; dz++)
#pragma unroll
      for (int dy = 0; dy < 2; dy++)
        act |= *(const uint16_t*)&t4[((b * 8 + 2 * oz + dz) * 8 + 2 * oy + dy) * 8 + 2 * ox];
    uint8_t v = act ? 1 : 0;
    t5[j] = v;
    m5[j] = v;
  }
  __syncthreads();
  if (tid < 64) {
    int j = tid;
    int ox = j & 1, oy = (j >> 1) & 1, oz = (j >> 2) & 1, b = j >> 3;
    uint32_t act = 0;
#pragma unroll
    for (int dz = 0; dz < 2; dz++)
#pragma unroll
      for (int dy = 0; dy < 2; dy++)
        act |= *(const uint16_t*)&t5[((b * 4 + 2 * oz + dz) * 4 + 2 * oy + dy) * 4 + 2 * ox];
    m6[j] = act ? 1 : 0;
  }
}

// ---------------- layer 0 conv: 16x16x8 tile; branch-free staging; 4 blocks/CU --------------
// MEASURED OPTIMUM (83 us). (256,4)=128-VGPR cap, 44 VGPR, no spill. Closed levers:
// caps <=64 spill (R8/R13/R14); 16^3 tile regressed (R16); row-per-thread neutral (R18).
__global__ __launch_bounds__(256, 4) void conv0_k(const float* __restrict__ x,
                                                  const uint8_t* __restrict__ m0,
                                                  const float* __restrict__ w,  // [27][1][2]
                                                  __hip_bfloat16* __restrict__ y0,
                                                  float* __restrict__ partials) {
  constexpr int SR = 26;     // LDS row stride (floats); slots 1..24 used
  constexpr int NROW = 180;  // 18 y * 10 z
  constexpr int ROUNDS = 5;  // 1080 quad tasks / 256
  __shared__ float sx[NROW * SR];
  __shared__ float sm[4][5];
  int blk = xswz(blockIdx.x, 8192);
  int tx0 = (blk & 7) * 16, ty0 = ((blk >> 3) & 7) * 16, tz0 = ((blk >> 6) & 15) * 8,
      b = blk >> 10;
  int tid = threadIdx.x;

  // phase 1: issue all staging loads (aligned float4 + u32 mask; per-quad validity)
  float4 xq[ROUNDS];
  uint32_t mq[ROUNDS];
#pragma unroll
  for (int r = 0; r < ROUNDS; r++) {
    unsigned i = tid + 256u * r;
    unsigned row = (i * 43691u) >> 18;  // i/6 (valid i<1280)
    int k = (int)(i - row * 6u);
    unsigned sz = (row * 3641u) >> 16;  // row/18 (valid row<2000)
    int sy = (int)(row - sz * 18u);
    int gz = tz0 + (int)sz - 1, gy = ty0 + sy - 1;
    int gx4 = tx0 - 4 + 4 * k;
    bool ok = (row < (unsigned)NROW) & ((unsigned)gz < 128u) & ((unsigned)gy < 128u) &
              ((unsigned)gx4 < 128u);  // quads are fully in or fully out
    int gi = ok ? ((b * 128 + gz) * 128 + gy) * 128 + gx4 : 0;
    xq[r] = *(const float4*)(x + gi);
    uint32_t mr = *(const uint32_t*)(m0 + gi);
    mq[r] = ok ? mr : 0u;
  }
  // phase 2: unconditional b32 stores, value-selected (no exec churn); slot = 4k+1+e
#pragma unroll
  for (int r = 0; r < ROUNDS; r++) {
    unsigned i = tid + 256u * r;
    unsigned row = (i * 43691u) >> 18;
    int k = (int)(i - row * 6u);
    if (row < (unsigned)NROW) {
      float vals[4] = {xq[r].x, xq[r].y, xq[r].z, xq[r].w};
      uint32_t mw = mq[r];
      int base = (int)row * SR + 4 * k + 1;
#pragma unroll
      for (int e = 0; e < 4; e++)
        sx[base + e] = ((mw >> (8 * e)) & 0xffu) ? vals[e] : 0.f;
    }
  }
  __syncthreads();

  int tc = tid & 7, tb = (tid >> 3) & 7, ta = tid >> 6;  // ta 0..3
  int lx = tc * 2, ly = tb * 2, lz = ta * 2;

  // hoist stat-mask loads (L2-hot)
  uint32_t mm[2][2];
#pragma unroll
  for (int oz = 0; oz < 2; oz++)
#pragma unroll
    for (int oy = 0; oy < 2; oy++) {
      int z = tz0 + lz + oz, y = ty0 + ly + oy, xx = tx0 + lx;
      mm[oz][oy] = *(const uint16_t*)(m0 + ((b * 128 + z) * 128 + y) * 128 + xx);
    }

  float acc[2][2][2][2];
#pragma unroll
  for (int oz = 0; oz < 2; oz++)
#pragma unroll
    for (int oy = 0; oy < 2; oy++)
#pragma unroll
      for (int ox = 0; ox < 2; ox++)
        acc[oz][oy][ox][0] = acc[oz][oy][ox][1] = 0.f;

  // z-plane streaming; pl[yy][j] = input at gx = tx0+lx-1+j (slot lx+4+j, even base -> b64)
#pragma unroll
  for (int p = 0; p < 4; p++) {
    float pl[4][4];
#pragma unroll
    for (int yy = 0; yy < 4; yy++)
#pragma unroll
      for (int j = 0; j < 4; j += 2) {
        float2 v = *(const float2*)&sx[((lz + p) * 18 + (ly + yy)) * SR + lx + 4 + j];
        pl[yy][j] = v.x;
        pl[yy][j + 1] = v.y;
      }
#pragma unroll
    for (int oz = 0; oz < 2; oz++) {
      int dz = p - oz;
      if (dz < 0 || dz > 2) continue;
#pragma unroll
      for (int dy = 0; dy < 3; dy++)
#pragma unroll
        for (int dx = 0; dx < 3; dx++) {
          float w0 = w[((dz * 3 + dy) * 3 + dx) * 2];
          float w1 = w[((dz * 3 + dy) * 3 + dx) * 2 + 1];
#pragma unroll
          for (int oy = 0; oy < 2; oy++)
#pragma unroll
            for (int ox = 0; ox < 2; ox++) {
              float s = pl[oy + dy][ox + dx];
              acc[oz][oy][ox][0] = fmaf(s, w0, acc[oz][oy][ox][0]);
              acc[oz][oy][ox][1] = fmaf(s, w1, acc[oz][oy][ox][1]);
            }
        }
    }
  }

  // store (-inf at inactive) + masked stats
  float s0 = 0.f, q0 = 0.f, s1 = 0.f, q1 = 0.f;
  int cnt2 = 0;
#pragma unroll
  for (int oz = 0; oz < 2; oz++)
#pragma unroll
    for (int oy = 0; oy < 2; oy++) {
      int z = tz0 + lz + oz, y = ty0 + ly + oy, xx = tx0 + lx;
      int vo = ((b * 128 + z) * 128 + y) * 128 + xx;
      uint32_t m2b = mm[oz][oy];
      uint2 st;
      if (m2b & 0xff) {
        st.x = f2bf(acc[oz][oy][0][0]) | (f2bf(acc[oz][oy][0][1]) << 16);
        s0 += acc[oz][oy][0][0];
        q0 += acc[oz][oy][0][0] * acc[oz][oy][0][0];
        s1 += acc[oz][oy][0][1];
        q1 += acc[oz][oy][0][1] * acc[oz][oy][0][1];
        cnt2++;
      } else {
        st.x = NEGINF_BF | (NEGINF_BF << 16);
      }
      if (m2b >> 8) {
        st.y = f2bf(acc[oz][oy][1][0]) | (f2bf(acc[oz][oy][1][1]) << 16);
        s0 += acc[oz][oy][1][0];
        q0 += acc[oz][oy][1][0] * acc[oz][oy][1][0];
        s1 += acc[oz][oy][1][1];
        q1 += acc[oz][oy][1][1] * acc[oz][oy][1][1];
        cnt2++;
      } else {
        st.y = NEGINF_BF | (NEGINF_BF << 16);
      }
      ((uint2*)y0)[vo >> 1] = st;
    }
  float cf = (float)cnt2;
#pragma unroll
  for (int off = 32; off >= 1; off >>= 1) {
    s0 += __shfl_xor(s0, off);
    q0 += __shfl_xor(q0, off);
    s1 += __shfl_xor(s1, off);
    q1 += __shfl_xor(q1, off);
    cf += __shfl_xor(cf, off);
  }
  int wave = tid >> 6;
  if ((tid & 63) == 0) {
    sm[wave][0] = s0;
    sm[wave][1] = q0;
    sm[wave][2] = s1;
    sm[wave][3] = q1;
    sm[wave][4] = cf;
  }
  __syncthreads();
  if (tid < 5) {
    float t = 0.f;
#pragma unroll
    for (int wv = 0; wv < 4; wv++) t += sm[wv][tid];
    partials[blk * 5 + tid] = t;
  }
}

// ---------------- LDS-tiled stride-2 conv (bf16 in); -inf sentinel -------------------------
// Cin==2: quad-of-voxels uint4 staging. Cin==4: voxel-pair uint4 staging.
template <int Din, int Cin, int Cout, int TZ, typename Tin, typename Tout>
__global__ __launch_bounds__(64 * TZ, 4) void conv_tile_k(const Tin* __restrict__ yin,
                                                          const uint8_t* __restrict__ mo,
                                                          const float* __restrict__ ssin,
                                                          const float* __restrict__ w,
                                                          Tout* __restrict__ yout,
                                                          float* __restrict__ partials) {
  static_assert(sizeof(Tin) == 2 && (Cin == 2 || Cin == 4), "bf16 input only");
  constexpr int Dout = Din / 2;
  constexpr int NT = 64 * TZ;
  constexpr int IZ = 2 * TZ + 1;
  constexpr int NROW = 17 * IZ;
  constexpr int NTASK = (Cin == 2) ? NROW * 5 : NROW * 9;
  constexpr int PR = (NTASK + NT - 1) / NT;
  constexpr int TXN = Dout / 8;
  constexpr int TZN = Dout / TZ;
  constexpr int LTX = il2(TXN);
  constexpr int LTZ = il2(TZN);
  constexpr int NWG = TXN * TXN * TZN * BATCH;
  constexpr int REC = 2 * Cout + 1;
  __shared__ float sx[289 * IZ * Cin];
  __shared__ float sm[TZ][REC];

  int tid = threadIdx.x;
  int blk = xswz(blockIdx.x, NWG);
  int tx0 = (blk & (TXN - 1)) * 8;
  int ty0 = ((blk >> LTX) & (TXN - 1)) * 8;
  int tz0 = ((blk >> (2 * LTX)) & (TZN - 1)) * TZ;
  int b = blk >> (2 * LTX + LTZ);

  float sc[Cin], sh[Cin];
#pragma unroll
  for (int ci = 0; ci < Cin; ci++) {
    sc[ci] = ssin[2 * ci];
    sh[ci] = ssin[2 * ci + 1];
  }

  int oy0 = 2 * ty0 - 1, oz0 = 2 * tz0 - 1;
  // phase 1: issue all staging loads (clamped addresses)
  uint4 pv[PR];
  uint32_t okb = 0;
#pragma unroll
  for (int r = 0; r < PR; r++) {
    int i = tid + r * NT;
    if constexpr (Cin == 2) {
      int row = i / 5, qq = i - 5 * row;
      int sz = row / 17, sy = row - 17 * sz;
      int gz = oz0 + sz, gy = oy0 + sy;
      int px = 2 * tx0 - 4 + 4 * qq;  // 4-voxel window [2tx0-4, 2tx0+16)
      bool ok = (i < NTASK) & ((unsigned)gz < (unsigned)Din) & ((unsigned)gy < (unsigned)Din) &
                (px >= 0);
      int gi = ok ? ((b * Din + gz) * Din + gy) * Din + px : 0;
      if (ok) okb |= (1u << r);
      pv[r] = *(const uint4*)((const uint16_t*)yin + (size_t)gi * 2);
    } else {
      int row = i / 9, qq = i - 9 * row;
      int sz = row / 17, sy = row - 17 * sz;
      int gz = oz0 + sz, gy = oy0 + sy;
      int px = 2 * tx0 - 2 + 2 * qq;  // voxel pair
      bool ok = (i < NTASK) & ((unsigned)gz < (unsigned)Din) & ((unsigned)gy < (unsigned)Din) &
                (px >= 0);
      int gi = ok ? ((b * Din + gz) * Din + gy) * Din + px : 0;
      if (ok) okb |= (1u << r);
      pv[r] = *(const uint4*)((const uint16_t*)yin + (size_t)gi * 4);
    }
  }
  // phase 2: BN+ReLU then LDS writes (-inf sentinel -> 0 automatically)
#pragma unroll
  for (int r = 0; r < PR; r++) {
    int i = tid + r * NT;
    if (i >= NTASK) continue;
    bool ok = (okb >> r) & 1u;
    if constexpr (Cin == 2) {
      int row = i / 5, qq = i - 5 * row;
      uint32_t vox[4] = {pv[r].x, pv[r].y, pv[r].z, pv[r].w};
#pragma unroll
      for (int e = 0; e < 4; e++) {
        int u = 4 * qq + e - 3;
        if ((unsigned)u >= 17u) continue;
        int site = row * 17 + u;
        float f0 = ok ? fmaxf(fmaf(bflo(vox[e]), sc[0], sh[0]), 0.f) : 0.f;
        float f1 = ok ? fmaxf(fmaf(bfhi(vox[e]), sc[1], sh[1]), 0.f) : 0.f;
        *(float2*)&sx[site * 2] = make_float2(f0, f1);
      }
    } else {
      int row = i / 9, qq = i - 9 * row;
#pragma unroll
      for (int e = 0; e < 2; e++) {
        int u = 2 * qq - 1 + e;
        if ((unsigned)u >= 17u) continue;
        int site = row * 17 + u;
        uint32_t va = e ? pv[r].z : pv[r].x;
        uint32_t vb = e ? pv[r].w : pv[r].y;
        float f0 = ok ? fmaxf(fmaf(bflo(va), sc[0], sh[0]), 0.f) : 0.f;
        float f1 = ok ? fmaxf(fmaf(bfhi(va), sc[1], sh[1]), 0.f) : 0.f;
        float f2 = ok ? fmaxf(fmaf(bflo(vb), sc[2], sh[2]), 0.f) : 0.f;
        float f3 = ok ? fmaxf(fmaf(bfhi(vb), sc[3], sh[3]), 0.f) : 0.f;
        *(float4*)&sx[site * 4] = make_float4(f0, f1, f2, f3);
      }
    }
  }
  __syncthreads();

  int tc = tid & 7, tb = (tid >> 3) & 7, ta = tid >> 6;
  int lx = tc, ly = tb, lz = ta;
  int vo = ((b * Dout + tz0 + lz) * Dout + ty0 + ly) * Dout + tx0 + lx;
  bool act = mo[vo] != 0;
  float acc[Cout];
#pragma unroll
  for (int co = 0; co < Cout; co++) acc[co] = 0.f;
  if (act) {
    int base = ((2 * lz) * 289 + (2 * ly) * 17 + (2 * lx)) * Cin;
#pragma unroll
    for (int dz = 0; dz < 3; dz++)
#pragma unroll
      for (int dy = 0; dy < 3; dy++)
#pragma unroll
        for (int dx = 0; dx < 3; dx++) {
          int off = base + (dz * 289 + dy * 17 + dx) * Cin;
          const float* wp = w + ((dz * 3 + dy) * 3 + dx) * Cin * Cout;
#pragma unroll
          for (int ci = 0; ci < Cin; ci++) {
            float s = sx[off + ci];
#pragma unroll
            for (int co = 0; co < Cout; co++)
              acc[co] = fmaf(s, wp[ci * Cout + co], acc[co]);
          }
        }
  }
  {
    uint32_t pk[Cout / 2];
    if (act) {
#pragma unroll
      for (int k = 0; k < Cout / 2; k++) pk[k] = f2bf(acc[2 * k]) | (f2bf(acc[2 * k + 1]) << 16);
    } else {
#pragma unroll
      for (int k = 0; k < Cout / 2; k++) pk[k] = NEGINF_BF | (NEGINF_BF << 16);
    }
    if constexpr (Cout == 4)
      *(uint2*)((uint16_t*)yout + (size_t)vo * 4) = *(uint2*)pk;
    else if constexpr (Cout == 8)
      *(uint4*)((uint16_t*)yout + (size_t)vo * 8) = *(uint4*)pk;
    else {
#pragma unroll
      for (int k = 0; k < Cout / 2; k++)
        *((uint32_t*)yout + (size_t)vo * (Cout / 2) + k) = pk[k];
    }
  }
  unsigned long long bal = __ballot(act);
  int wave = tid >> 6, lane = tid & 63;
#pragma unroll
  for (int co = 0; co < Cout; co++) {
    float s = acc[co], q = acc[co] * acc[co];
#pragma unroll
    for (int off = 32; off >= 1; off >>= 1) {
      s += __shfl_xor(s, off);
      q += __shfl_xor(q, off);
    }
    if (lane == 0) {
      sm[wave][2 * co] = s;
      sm[wave][2 * co + 1] = q;
    }
  }
  if (lane == 0) sm[wave][2 * Cout] = (float)__popcll(bal);
  __syncthreads();
  if (tid < REC) {
    float t = 0.f;
#pragma unroll
    for (int wv = 0; wv < TZ; wv++) t += sm[wv][tid];
    partials[(size_t)blk * REC + tid] = t;
  }
}

// ---------------- generic stride-2 conv (small layers); -inf sentinel input ----------------
template <int Din, int Cin, int Cout, typename Tin, typename Tout>
__global__ __launch_bounds__(256) void conv_s2_k(const Tin* __restrict__ yin,
                                                 const uint8_t* __restrict__ mo,
                                                 const float* __restrict__ ssin,
                                                 const float* __restrict__ w,
                                                 Tout* __restrict__ yout,
                                                 float* __restrict__ partials) {
  constexpr int Dout = Din / 2;
  constexpr int LD = il2(Dout);
  constexpr int LC = il2(Cout);
  constexpr int REC = 2 * Cout + 1;
  int tid = threadIdx.x;
  int lin = blockIdx.x * 256 + tid;
  int co = lin & (Cout - 1);
  int v = lin >> LC;
  int x = v & (Dout - 1);
  int y = (v >> LD) & (Dout - 1);
  int z = (v >> (2 * LD)) & (Dout - 1);
  int b = v >> (3 * LD);
  bool act = mo[v] != 0;
  float acc = 0.f;
  if (act) {
    for (int dz = 0; dz < 3; dz++) {
      int iz = 2 * z + dz - 1;
      if ((unsigned)iz >= (unsigned)Din) continue;
      for (int dy = 0; dy < 3; dy++) {
        int iy = 2 * y + dy - 1;
        if ((unsigned)iy >= (unsigned)Din) continue;
        for (int dx = 0; dx < 3; dx++) {
          int ix = 2 * x + dx - 1;
          if ((unsigned)ix >= (unsigned)Din) continue;
          int gi = ((b * Din + iz) * Din + iy) * Din + ix;
          const float* wp = w + ((dz * 3 + dy) * 3 + dx) * Cin * Cout + co;
          float f[Cin];
          if constexpr (sizeof(Tin) == 2 && Cin == 8) {
            uint4 rr = *(const uint4*)((const uint16_t*)yin + (size_t)gi * 8);
            f[0] = bflo(rr.x);
            f[1] = bfhi(rr.x);
            f[2] = bflo(rr.y);
            f[3] = bfhi(rr.y);
            f[4] = bflo(rr.z);
            f[5] = bfhi(rr.z);
            f[6] = bflo(rr.w);
            f[7] = bfhi(rr.w);
          } else if constexpr (sizeof(Tin) == 4 && (Cin % 4) == 0) {
            const float* yp = (const float*)yin + (size_t)gi * Cin;
#pragma unroll
            for (int c4 = 0; c4 < Cin; c4 += 4) {
              float4 vv = *(const float4*)(yp + c4);
              f[c4] = vv.x;
              f[c4 + 1] = vv.y;
              f[c4 + 2] = vv.z;
              f[c4 + 3] = vv.w;
            }
          } else {
            const Tin* yp = yin + (size_t)gi * Cin;
#pragma unroll
            for (int ci = 0; ci < Cin; ci++) f[ci] = ldy(yp, ci);
          }
#pragma unroll
          for (int ci = 0; ci < Cin; ci++) {
            float val = fmaxf(fmaf(f[ci], ssin[2 * ci], ssin[2 * ci + 1]), 0.f);
            acc = fmaf(val, wp[ci * Cout], acc);
          }
        }
      }
    }
  }
  sty(yout, (size_t)lin, act ? acc : -INFINITY);
  float s = acc, q = acc * acc;
#pragma unroll
  for (int off = 32; off >= Cout; off >>= 1) {
    s += __shfl_xor(s, off);
    q += __shfl_xor(q, off);
  }
  unsigned long long bal = __ballot(act && co == 0);
  __shared__ float sm[4][REC];
  int wave = tid >> 6, lane = tid & 63;
  if (lane < Cout) {
    sm[wave][2 * lane] = s;
    sm[wave][2 * lane + 1] = q;
  }
  if (lane == 0) sm[wave][2 * Cout] = (float)__popcll(bal);
  __syncthreads();
  if (tid < REC)
    partials[(size_t)blockIdx.x * REC + tid] = sm[0][tid] + sm[1][tid] + sm[2][tid] + sm[3][tid];
}

// ---------------- stat reduce: partials -> per-channel (scale, shift) ----------------
template <int Cout>
__global__ __launch_bounds__(256) void stats_k(const float* __restrict__ partials, int nblocks,
                                               const float* __restrict__ g,
                                               const float* __restrict__ bb,
                                               float* __restrict__ ss) {
  constexpr int REC = 2 * Cout + 1;
  int c = blockIdx.x, tid = threadIdx.x;
  float s = 0.f, q = 0.f, n = 0.f;
  for (int i = tid; i < nblocks; i += 256) {
    const float* p = partials + (size_t)i * REC;
    s += p[2 * c];
    q += p[2 * c + 1];
    n += p[2 * Cout];
  }
  __shared__ float S[256], Q[256], N[256];
  S[tid] = s;
  Q[tid] = q;
  N[tid] = n;
  __syncthreads();
  for (int st = 128; st > 0; st >>= 1) {
    if (tid < st) {
      S[tid] += S[tid + st];
      Q[tid] += Q[tid + st];
      N[tid] += N[tid + st];
    }
    __syncthreads();
  }
  if (tid == 0) {
    float cnt = fmaxf(N[0], 1.f);
    float mean = S[0] / cnt;
    float var = Q[0] / cnt - mean * mean;
    float scale = g[c] * rsqrtf(var + 1e-5f);
    ss[2 * c] = scale;
    ss[2 * c + 1] = bb[c] - mean * scale;
  }
}

// ---------------- final: fused stats<64> + sparse max pool (-inf sentinel input) -------------
__global__ __launch_bounds__(512) void pool_stats_k(const float* __restrict__ y5,
                                                    const uint8_t* __restrict__ m6,
                                                    const float* __restrict__ partials,  // 128x129
                                                    const float* __restrict__ g,
                                                    const float* __restrict__ bb,
                                                    float* __restrict__ out) {
  __shared__ float ssc[64], ssh[64];
  int b = blockIdx.x, tid = threadIdx.x;
  if (tid < 64) {
    float s = 0.f, q = 0.f, n = 0.f;
    for (int i = 0; i < 128; i++) {
      const float* p = partials + i * 129;
      s += p[2 * tid];
      q += p[2 * tid + 1];
      n += p[128];
    }
    float cnt = fmaxf(n, 1.f);
    float mean = s / cnt;
    float var = q / cnt - mean * mean;
    float scale = g[tid] * rsqrtf(var + 1e-5f);
    ssc[tid] = scale;
    ssh[tid] = bb[tid] - mean * scale;
  }
  __syncthreads();
  int c = tid & 63, s = tid >> 6;
  int qx = s & 1, qy = (s >> 1) & 1, qz = (s >> 2) & 1;
  int ov = ((b * 2 + qz) * 2 + qy) * 2 + qx;
  float scale = ssc[c], shift = ssh[c];
  float mx = 0.f;
  for (int dz = 0; dz < 3; dz++) {
    int iz = 2 * qz + dz - 1;
    if ((unsigned)iz >= 4u) continue;
    for (int dy = 0; dy < 3; dy++) {
      int iy = 2 * qy + dy - 1;
      if ((unsigned)iy >= 4u) continue;
      for (int dx = 0; dx < 3; dx++) {
        int ix = 2 * qx + dx - 1;
        if ((unsigned)ix >= 4u) continue;
        int gi = ((b * 4 + iz) * 4 + iy) * 4 + ix;
        float val = fmaxf(fmaf(y5[gi * 64 + c], scale, shift), 0.f);
        mx = fmaxf(mx, val);
      }
    }
  }
  // m6 gate is REQUIRED: inactive output can still see active neighbors in its 3^3 footprint
  out[ov * 64 + c] = m6[ov] ? mx : 0.f;
}

extern "C" void kernel_launch(void* const* d_in, const int* in_sizes, int n_in,
                              void* d_out, int out_size, void* d_ws, size_t ws_size,
                              hipStream_t stream) {
  const float* x = (const float*)d_in[0];
  const int* msk = (const int*)d_in[1];
  const float *w[6], *g[6], *bb[6];
  for (int i = 0; i < 6; i++) {
    w[i] = (const float*)d_in[2 + 3 * i];
    g[i] = (const float*)d_in[3 + 3 * i];
    bb[i] = (const float*)d_in[4 + 3 * i];
  }

  char* ws = (char*)d_ws;
  size_t o = 0;
  auto A = [&](size_t bytes) -> char* {
    char* p = ws + o;
    o = (o + bytes + 255) & ~(size_t)255;
    return p;
  };
  __hip_bfloat16* y0 = (__hip_bfloat16*)A(33554432 * 2);  // 64 MB
  __hip_bfloat16* y1 = (__hip_bfloat16*)A(8388608 * 2);   // 16 MB
  __hip_bfloat16* y2 = (__hip_bfloat16*)A(2097152 * 2);   // 4 MB
  float* y3 = (float*)A(2097152);
  float* y4 = (float*)A(524288);
  float* y5 = (float*)A(131072);
  uint8_t* m0 = (uint8_t*)A(16777216);
  uint8_t* m1 = (uint8_t*)A(2097152);
  uint8_t* m2 = (uint8_t*)A(262144);
  uint8_t* m3 = (uint8_t*)A(32768);
  uint8_t* m4 = (uint8_t*)A(4096);
  uint8_t* m5 = (uint8_t*)A(512);
  uint8_t* m6 = (uint8_t*)A(64);
  float* part = (float*)A(2 << 20);
  float* ss = (float*)A(4096);
  if (o > ws_size) return;  // cannot run safely

  maskA_k<<<512, 256, 0, stream>>>(msk, m0, m1, m2);
  maskB_k<<<1, 1024, 0, stream>>>(m2, m3, m4, m5, m6);

  conv0_k<<<8192, 256, 0, stream>>>(x, m0, w[0], y0, part);
  stats_k<2><<<2, 256, 0, stream>>>(part, 8192, g[0], bb[0], ss + 0);
  conv_tile_k<128, 2, 4, 4, __hip_bfloat16, __hip_bfloat16>
      <<<8192, 256, 0, stream>>>(y0, m1, ss + 0, w[1], y1, part);
  stats_k<4><<<4, 256, 0, stream>>>(part, 8192, g[1], bb[1], ss + 128);
  conv_tile_k<64, 4, 8, 4, __hip_bfloat16, __hip_bfloat16>
      <<<1024, 256, 0, stream>>>(y1, m2, ss + 128, w[2], y2, part);
  stats_k<8><<<8, 256, 0, stream>>>(part, 1024, g[2], bb[2], ss + 256);
  conv_s2_k<32, 8, 16, __hip_bfloat16, float>
      <<<2048, 256, 0, stream>>>(y2, m3, ss + 256, w[3], y3, part);
  stats_k<16><<<16, 256, 0, stream>>>(part, 2048, g[3], bb[3], ss + 384);
  conv_s2_k<16, 16, 32, float, float>
      <<<512, 256, 0, stream>>>(y3, m4, ss + 384, w[4], y4, part);
  stats_k<32><<<32, 256, 0, stream>>>(part, 512, g[4], bb[4], ss + 512);
  conv_s2_k<8, 32, 64, float, float>
      <<<128, 256, 0, stream>>>(y4, m5, ss + 512, w[5], y5, part);
  pool_stats_k<<<8, 512, 0, stream>>>(y5, m6, part, g[5], bb[5], (float*)d_out);
}